// Round 1
// baseline (69419.446 us; speedup 1.0000x reference)
//
#include <hip/hip_runtime.h>
#include <hip/hip_bf16.h>

#define HID 1024
#define BATCH 128
#define TSTEPS 512
#define NWG 256
#define NTHR 512

typedef __bf16 bf16x8 __attribute__((ext_vector_type(8)));
typedef float f32x4 __attribute__((ext_vector_type(4)));

__device__ __forceinline__ float sigm(float x){ return 1.f/(1.f+__expf(-x)); }

__device__ __forceinline__ bf16x8 cvt8(const float* __restrict__ p){
  bf16x8 r;
  #pragma unroll
  for (int i=0;i<8;i++) r[i] = (__bf16)p[i];
  return r;
}
__device__ __forceinline__ bf16x8 cvt8s(const float* __restrict__ p, float s){
  bf16x8 r;
  #pragma unroll
  for (int i=0;i<8;i++) r[i] = (__bf16)(p[i]*s);
  return r;
}

// Zero barrier state (ws is poisoned 0xAA by harness) and convert z -> bf16 h0buf.
__global__ void init_kernel(const float* __restrict__ z,
                            unsigned short* __restrict__ h0buf,
                            unsigned* __restrict__ bar){
  int i = blockIdx.x*blockDim.x + threadIdx.x;
  if (i < 512) bar[i] = 0u;
  for (int j = i; j < BATCH*HID; j += gridDim.x*blockDim.x)
    h0buf[j] = __builtin_bit_cast(unsigned short, (__bf16)z[j]);
}

__global__ __launch_bounds__(NTHR, 2) void lstm_kernel(
    const float* __restrict__ seq,
    const float* __restrict__ z,
    const float* __restrict__ Wih0, const float* __restrict__ Whh0,
    const float* __restrict__ bih0, const float* __restrict__ bhh0,
    const float* __restrict__ Wih1, const float* __restrict__ Whh1,
    const float* __restrict__ bih1, const float* __restrict__ bhh1,
    const float* __restrict__ Wout, const float* __restrict__ bout,
    float* __restrict__ out,
    unsigned short* __restrict__ h0buf,
    unsigned short* __restrict__ h1buf,
    float* __restrict__ predpart,
    float* __restrict__ losspart,
    unsigned* __restrict__ bar)
{
  const int tid = threadIdx.x;
  const int wg  = blockIdx.x;
  const int wid = tid >> 6;
  const int lane = tid & 63;
  const int u0 = wg << 2;           // this WG owns hidden units [u0, u0+4) in both layers

  __shared__ float red[4][2048];    // cross-wave K-partial reduction (32KB)
  __shared__ float finals[2048];    // reduced gates [128 b][16 cols] (8KB)
  __shared__ float pr[8];
  __shared__ float sb0p[16], sb0f[16], sb1[16];

  const float bout_s = bout[0];

  if (tid < 16) {
    int g = tid >> 2, du = tid & 3;
    int gc = g*HID + u0 + du;
    float bp = bih0[gc] + bhh0[gc];
    sb0p[tid] = bp;                       // layer0 bias, t==0 (pred = 0)
    sb0f[tid] = bp + Wih0[gc]*bout_s;     // layer0 bias with folded b_out term
    sb1[tid]  = bih1[gc] + bhh1[gc];
  }

  // elementwise cell mapping: thread -> (batch eb, unit-offset edu)
  const int eb = tid >> 2;
  const int edu = tid & 3;
  const float wout_u = Wout[u0 + edu];
  float c0 = z[eb*HID + u0 + edu];        // c init = z (both layers)
  float c1 = c0;

  // ---- persistent weight fragments (MFMA B-operand layout) ----
  // virtual col j = gate*4 + du ; B[k][j]: j = lane&15, k = (lane>>4)*8 + e
  const int bcol = lane & 15;
  const int gcol = (bcol >> 2)*HID + u0 + (bcol & 3);
  const int ksub = (lane >> 4) << 3;
  bf16x8 w_hh0[4], w_ih1[4], w_hh1[4], w_fold[4];
  {
    const float wih0c = Wih0[gcol];
    #pragma unroll
    for (int kt=0; kt<4; ++kt) {
      int k0 = (wid << 7) + (kt << 5) + ksub;   // wave owns K-slice [wid*128, wid*128+128)
      w_hh0[kt]  = cvt8(Whh0 + gcol*HID + k0);
      w_ih1[kt]  = cvt8(Wih1 + gcol*HID + k0);
      w_hh1[kt]  = cvt8(Whh1 + gcol*HID + k0);
      w_fold[kt] = cvt8s(Wout + k0, wih0c);     // W_fold[c][u] = W_ih0[c]*w_out[u]
    }
  }

  // A-operand base: row = m*16 + (lane&15), k = wid*128 + kt*32 + (lane>>4)*8
  const int abase = (lane & 15)*HID + (wid << 7) + ksub;

  f32x4 accG0[8], accG1[8];
  #pragma unroll
  for (int m=0;m<8;m++){ accG0[m] = f32x4{0,0,0,0}; accG1[m] = f32x4{0,0,0,0}; }

  unsigned gen = 0;

  // one pass over an h buffer feeds TWO weight sets (A-frag reuse)
  auto do_pass = [&](const unsigned short* __restrict__ src,
                     const bf16x8* wA, const bf16x8* wB,
                     f32x4* accA, f32x4* accB){
    #pragma unroll
    for (int kt=0; kt<4; ++kt){
      bf16x8 af[8];
      #pragma unroll
      for (int m=0;m<8;m++)
        af[m] = *reinterpret_cast<const bf16x8*>(src + abase + (kt<<5) + m*16*HID);
      #pragma unroll
      for (int m=0;m<8;m++){
        accA[m] = __builtin_amdgcn_mfma_f32_16x16x32_bf16(af[m], wA[kt], accA[m], 0, 0, 0);
        accB[m] = __builtin_amdgcn_mfma_f32_16x16x32_bf16(af[m], wB[kt], accB[m], 0, 0, 0);
      }
    }
  };

  // reduce 8 wave K-partials -> finals[b*16+col] (+bias); zeroes acc
  auto reduce_finals = [&](f32x4* acc, const float* sbias){
    const int rbase = ((lane>>4)<<6) + (lane & 15);   // (row_in_tile)*16 + col
    if (wid < 4) {
      #pragma unroll
      for (int m=0;m<8;m++){
        int p = rbase + (m<<8);
        #pragma unroll
        for (int e=0;e<4;e++) red[wid][p + (e<<4)] = acc[m][e];
      }
    }
    __syncthreads();
    if (wid >= 4) {
      #pragma unroll
      for (int m=0;m<8;m++){
        int p = rbase + (m<<8);
        #pragma unroll
        for (int e=0;e<4;e++) red[wid-4][p + (e<<4)] += acc[m][e];
      }
    }
    __syncthreads();
    for (int i=tid; i<2048; i+=NTHR)
      finals[i] = red[0][i]+red[1][i]+red[2][i]+red[3][i] + sbias[i & 15];
    __syncthreads();
    #pragma unroll
    for (int m=0;m<8;m++) acc[m] = f32x4{0,0,0,0};
  };

  auto elementwise = [&](float& c, unsigned short* __restrict__ hb, bool dopred){
    float gi = finals[(eb<<4) + edu];
    float gf = finals[(eb<<4) + 4 + edu];
    float gg = finals[(eb<<4) + 8 + edu];
    float go = finals[(eb<<4) + 12 + edu];
    float fi = sigm(gi), ff = sigm(gf), fo = sigm(go);
    c = ff*c + fi*tanhf(gg);
    float h = fo*tanhf(c);
    hb[eb*HID + u0 + edu] = __builtin_bit_cast(unsigned short, (__bf16)h);
    if (dopred){
      float pv = h * wout_u;                 // fp32 pred partial (pre-quantization h)
      pv += __shfl_xor(pv, 1);
      pv += __shfl_xor(pv, 2);
      if (edu == 0) predpart[(eb<<8) + wg] = pv;
    }
  };

  // hierarchical grid barrier: 8 groups x 32 blocks, monotone generation counter
  auto grid_barrier = [&](){
    __syncthreads();
    ++gen;
    if (tid == 0) {
      __threadfence();   // agent fence: flush block's stores past local L2
      unsigned g = (unsigned)(wg & 7);
      unsigned old = __hip_atomic_fetch_add(&bar[64 + g*32], 1u, __ATOMIC_ACQ_REL, __HIP_MEMORY_SCOPE_AGENT);
      if (old == 31u) {
        unsigned r = __hip_atomic_fetch_add(&bar[32], 1u, __ATOMIC_ACQ_REL, __HIP_MEMORY_SCOPE_AGENT);
        if (r == 7u) {
          #pragma unroll
          for (int i=0;i<8;i++)
            __hip_atomic_store(&bar[64+i*32], 0u, __ATOMIC_RELAXED, __HIP_MEMORY_SCOPE_AGENT);
          __hip_atomic_store(&bar[32], 0u, __ATOMIC_RELAXED, __HIP_MEMORY_SCOPE_AGENT);
          __hip_atomic_store(&bar[0], gen, __ATOMIC_RELEASE, __HIP_MEMORY_SCOPE_AGENT);
        }
      }
      while (__hip_atomic_load(&bar[0], __ATOMIC_ACQUIRE, __HIP_MEMORY_SCOPE_AGENT) < gen) {
        __builtin_amdgcn_s_sleep(2);
      }
    }
    __syncthreads();
    __threadfence();     // acquire side per wave: invalidate L1/L2 for fresh h reads
  };

  // ---- prologue: gates0[0] = z@Whh0 + b (pred=0); accG1 = z@Whh1 carry ----
  do_pass(h0buf, w_hh0, w_hh1, accG0, accG1);
  grid_barrier();                         // all reads of z done before overwrite
  reduce_finals(accG0, sb0p);
  elementwise(c0, h0buf, false);          // h0[0] -> h0buf
  grid_barrier();                         // publish h0[0]

  for (int t=0; t<TSTEPS; ++t) {
    // gates1[t] completes (h0[t]@Wih1 + carry); gates0[t+1] partial (h0[t]@Whh0)
    do_pass(h0buf, w_ih1, w_hh0, accG1, accG0);
    reduce_finals(accG1, sb1);
    elementwise(c1, h1buf, true);         // h1[t] + pred partials
    grid_barrier();                       // publish h1[t], predpart

    // gates0[t+1] completes (h1[t]@Wfold, folded pred); gates1[t+1] partial (h1[t]@Whh1)
    do_pass(h1buf, w_fold, w_hh1, accG0, accG1);
    reduce_finals(accG0, sb0f);
    elementwise(c0, h0buf, false);        // h0[t+1]

    // pred[t] reduction: block b (<128) sums 256 WG partials -> recovered[b][t]
    if (wg < BATCH) {
      float v = (tid < 256) ? predpart[(wg<<8) + tid] : 0.f;
      #pragma unroll
      for (int s=1; s<64; s<<=1) v += __shfl_xor(v, s);
      if (lane == 0) pr[wid] = v;
      __syncthreads();
      if (tid == 0) {
        float s = pr[0]+pr[1]+pr[2]+pr[3]+pr[4]+pr[5]+pr[6]+pr[7] + bout_s;
        out[1 + wg*TSTEPS + t] = s;
      }
    }
    grid_barrier();                       // publish h0[t+1]
  }

  // ---- loss epilogue: mean((seq - recovered)^2), deterministic order ----
  {
    int i = (wg<<8) + (tid & 255);
    float v = 0.f;
    if (tid < 256) { float d = seq[i] - out[1+i]; v = d*d; }
    #pragma unroll
    for (int s=1; s<64; s<<=1) v += __shfl_xor(v, s);
    if (lane == 0) pr[wid] = v;
    __syncthreads();
    if (tid == 0) losspart[wg] = pr[0]+pr[1]+pr[2]+pr[3]+pr[4]+pr[5]+pr[6]+pr[7];
  }
  grid_barrier();
  if (wg == 0 && tid == 0) {
    double s = 0.0;
    for (int j=0;j<NWG;j++) s += (double)losspart[j];
    out[0] = (float)(s / 65536.0);
  }
}

extern "C" void kernel_launch(void* const* d_in, const int* in_sizes, int n_in,
                              void* d_out, int out_size, void* d_ws, size_t ws_size,
                              hipStream_t stream)
{
  const float* seq  = (const float*)d_in[0];
  const float* z    = (const float*)d_in[1];
  const float* Wih0 = (const float*)d_in[2];
  const float* Whh0 = (const float*)d_in[3];
  const float* bih0 = (const float*)d_in[4];
  const float* bhh0 = (const float*)d_in[5];
  const float* Wih1 = (const float*)d_in[6];
  const float* Whh1 = (const float*)d_in[7];
  const float* bih1 = (const float*)d_in[8];
  const float* bhh1 = (const float*)d_in[9];
  const float* Wout = (const float*)d_in[10];
  const float* bout = (const float*)d_in[11];
  float* out = (float*)d_out;

  char* ws = (char*)d_ws;
  unsigned short* h0buf = (unsigned short*)(ws);                    // 256KB
  unsigned short* h1buf = (unsigned short*)(ws + 256*1024);         // 256KB
  float* predpart = (float*)(ws + 512*1024);                        // 128KB [b][wg]
  float* losspart = (float*)(ws + 640*1024);                        // 1KB
  unsigned* bar   = (unsigned*)(ws + 644*1024);                     // 2KB barrier state

  hipLaunchKernelGGL(init_kernel, dim3(128), dim3(256), 0, stream, z, h0buf, bar);

  void* args[] = { (void*)&seq, (void*)&z, (void*)&Wih0, (void*)&Whh0, (void*)&bih0, (void*)&bhh0,
                   (void*)&Wih1, (void*)&Whh1, (void*)&bih1, (void*)&bhh1, (void*)&Wout, (void*)&bout,
                   (void*)&out, (void*)&h0buf, (void*)&h1buf, (void*)&predpart, (void*)&losspart, (void*)&bar };
  hipLaunchCooperativeKernel((void*)lstm_kernel, dim3(NWG), dim3(NTHR), args, 0u, stream);
}

// Round 2
// 28389.117 us; speedup vs baseline: 2.4453x; 2.4453x over previous
//
#include <hip/hip_runtime.h>
#include <hip/hip_bf16.h>

#define HID 1024
#define BATCH 128
#define TSTEPS 512
#define NWG 256
#define NTHR 512

typedef __bf16 bf16x8 __attribute__((ext_vector_type(8)));
typedef float f32x4 __attribute__((ext_vector_type(4)));

__device__ __forceinline__ float sigm(float x){ return 1.f/(1.f+__expf(-x)); }

__device__ __forceinline__ bf16x8 cvt8(const float* __restrict__ p){
  bf16x8 r;
  #pragma unroll
  for (int i=0;i<8;i++) r[i] = (__bf16)p[i];
  return r;
}
__device__ __forceinline__ bf16x8 cvt8s(const float* __restrict__ p, float s){
  bf16x8 r;
  #pragma unroll
  for (int i=0;i<8;i++) r[i] = (__bf16)(p[i]*s);
  return r;
}

// Zero barrier state (ws is poisoned 0xAA by harness) and convert z -> bf16 h0buf.
__global__ void init_kernel(const float* __restrict__ z,
                            unsigned short* __restrict__ h0buf,
                            unsigned* __restrict__ bar){
  int i = blockIdx.x*blockDim.x + threadIdx.x;
  if (i < 512) bar[i] = 0u;
  for (int j = i; j < BATCH*HID; j += gridDim.x*blockDim.x)
    h0buf[j] = __builtin_bit_cast(unsigned short, (__bf16)z[j]);
}

__global__ __launch_bounds__(NTHR, 2) void lstm_kernel(
    const float* __restrict__ seq,
    const float* __restrict__ z,
    const float* __restrict__ Wih0, const float* __restrict__ Whh0,
    const float* __restrict__ bih0, const float* __restrict__ bhh0,
    const float* __restrict__ Wih1, const float* __restrict__ Whh1,
    const float* __restrict__ bih1, const float* __restrict__ bhh1,
    const float* __restrict__ Wout, const float* __restrict__ bout,
    float* __restrict__ out,
    unsigned short* __restrict__ h0buf,
    unsigned short* __restrict__ h1buf,
    float* __restrict__ predpart,
    float* __restrict__ losspart,
    unsigned* __restrict__ bar)
{
  const int tid = threadIdx.x;
  const int wg  = blockIdx.x;
  const int wid = tid >> 6;
  const int lane = tid & 63;
  const int u0 = wg << 2;           // this WG owns hidden units [u0, u0+4) in both layers

  __shared__ float red[4][2048];    // cross-wave K-partial reduction (32KB)
  __shared__ float finals[2048];    // reduced gates [128 b][16 cols] (8KB)
  __shared__ float pr[8];
  __shared__ float sb0p[16], sb0f[16], sb1[16];

  const float bout_s = bout[0];

  if (tid < 16) {
    int g = tid >> 2, du = tid & 3;
    int gc = g*HID + u0 + du;
    float bp = bih0[gc] + bhh0[gc];
    sb0p[tid] = bp;                       // layer0 bias, t==0 (pred = 0)
    sb0f[tid] = bp + Wih0[gc]*bout_s;     // layer0 bias with folded b_out term
    sb1[tid]  = bih1[gc] + bhh1[gc];
  }

  // elementwise cell mapping: thread -> (batch eb, unit-offset edu)
  const int eb = tid >> 2;
  const int edu = tid & 3;
  const float wout_u = Wout[u0 + edu];
  float c0 = z[eb*HID + u0 + edu];        // c init = z (both layers)
  float c1 = c0;
  float lossacc = 0.f;

  // ---- persistent weight fragments (MFMA B-operand layout) ----
  // virtual col j = gate*4 + du ; B[k][j]: j = lane&15, k = (lane>>4)*8 + e
  const int bcol = lane & 15;
  const int gcol = (bcol >> 2)*HID + u0 + (bcol & 3);
  const int ksub = (lane >> 4) << 3;
  bf16x8 w_hh0[4], w_ih1[4], w_hh1[4], w_fold[4];
  {
    const float wih0c = Wih0[gcol];
    #pragma unroll
    for (int kt=0; kt<4; ++kt) {
      int k0 = (wid << 7) + (kt << 5) + ksub;   // wave owns K-slice [wid*128, wid*128+128)
      w_hh0[kt]  = cvt8(Whh0 + gcol*HID + k0);
      w_ih1[kt]  = cvt8(Wih1 + gcol*HID + k0);
      w_hh1[kt]  = cvt8(Whh1 + gcol*HID + k0);
      w_fold[kt] = cvt8s(Wout + k0, wih0c);     // W_fold[c][u] = W_ih0[c]*w_out[u]
    }
  }

  // A-operand base: row = m*16 + (lane&15), k = wid*128 + kt*32 + (lane>>4)*8
  const int abase = (lane & 15)*HID + (wid << 7) + ksub;

  f32x4 accG0[8], accG1[8];
  #pragma unroll
  for (int m=0;m<8;m++){ accG0[m] = f32x4{0,0,0,0}; accG1[m] = f32x4{0,0,0,0}; }

  unsigned gen = 0;

  // one pass over an h buffer feeds TWO weight sets (A-frag reuse); plain cached loads
  auto do_pass = [&](const unsigned short* __restrict__ src,
                     const bf16x8* wA, const bf16x8* wB,
                     f32x4* accA, f32x4* accB){
    #pragma unroll
    for (int kt=0; kt<4; ++kt){
      bf16x8 af[8];
      #pragma unroll
      for (int m=0;m<8;m++)
        af[m] = *reinterpret_cast<const bf16x8*>(src + abase + (kt<<5) + m*16*HID);
      #pragma unroll
      for (int m=0;m<8;m++){
        accA[m] = __builtin_amdgcn_mfma_f32_16x16x32_bf16(af[m], wA[kt], accA[m], 0, 0, 0);
        accB[m] = __builtin_amdgcn_mfma_f32_16x16x32_bf16(af[m], wB[kt], accB[m], 0, 0, 0);
      }
    }
  };

  // reduce 8 wave K-partials -> finals[b*16+col] (+bias); zeroes acc
  auto reduce_finals = [&](f32x4* acc, const float* sbias){
    const int rbase = ((lane>>4)<<6) + (lane & 15);   // (row_in_tile)*16 + col
    if (wid < 4) {
      #pragma unroll
      for (int m=0;m<8;m++){
        int p = rbase + (m<<8);
        #pragma unroll
        for (int e=0;e<4;e++) red[wid][p + (e<<4)] = acc[m][e];
      }
    }
    __syncthreads();
    if (wid >= 4) {
      #pragma unroll
      for (int m=0;m<8;m++){
        int p = rbase + (m<<8);
        #pragma unroll
        for (int e=0;e<4;e++) red[wid-4][p + (e<<4)] += acc[m][e];
      }
    }
    __syncthreads();
    for (int i=tid; i<2048; i+=NTHR)
      finals[i] = red[0][i]+red[1][i]+red[2][i]+red[3][i] + sbias[i & 15];
    __syncthreads();
    #pragma unroll
    for (int m=0;m<8;m++) acc[m] = f32x4{0,0,0,0};
  };

  // h store: pack 2 units -> one 4B agent-scope (sc0 sc1) write-through store.
  auto elementwise = [&](float& c, unsigned short* __restrict__ hb, bool dopred){
    float gi = finals[(eb<<4) + edu];
    float gf = finals[(eb<<4) + 4 + edu];
    float gg = finals[(eb<<4) + 8 + edu];
    float go = finals[(eb<<4) + 12 + edu];
    float fi = sigm(gi), ff = sigm(gf), fo = sigm(go);
    c = ff*c + fi*tanhf(gg);
    float h = fo*tanhf(c);
    unsigned hb16 = (unsigned)__builtin_bit_cast(unsigned short, (__bf16)h);
    unsigned other = (unsigned)__shfl_xor((int)hb16, 1);
    if ((edu & 1) == 0) {
      unsigned word = hb16 | (other << 16);
      __hip_atomic_store((unsigned*)(hb + eb*HID + u0 + edu), word,
                         __ATOMIC_RELAXED, __HIP_MEMORY_SCOPE_AGENT);
    }
    if (dopred){
      float pv = h * wout_u;                 // fp32 pred partial (pre-quantization h)
      pv += __shfl_xor(pv, 1);
      pv += __shfl_xor(pv, 2);
      if (edu == 0)
        __hip_atomic_store(&predpart[(eb<<8) + wg], pv,
                           __ATOMIC_RELAXED, __HIP_MEMORY_SCOPE_AGENT);
    }
  };

  // Grid barrier: monotone hierarchical counters (8 groups x 32 WGs), all
  // RELAXED agent atomics (sc1 -> served at coherent L3). __syncthreads drains
  // each wave's vmcnt so all sc1 stores are at L3 before any arrival. Exit
  // does an acquire-only fence (buffer_inv, no wbl2) so plain cached loads of
  // h/predpart see fresh data while weights stay L2-resident.
  auto grid_barrier = [&](){
    __syncthreads();
    ++gen;
    if (tid == 0) {
      unsigned old = __hip_atomic_fetch_add(&bar[32 + (wg & 7)*32], 1u,
                        __ATOMIC_RELAXED, __HIP_MEMORY_SCOPE_AGENT);
      if (old == gen*32u - 1u) {
        unsigned r = __hip_atomic_fetch_add(&bar[8], 1u,
                        __ATOMIC_RELAXED, __HIP_MEMORY_SCOPE_AGENT);
        if (r == gen*8u - 1u)
          __hip_atomic_store(&bar[0], gen, __ATOMIC_RELAXED, __HIP_MEMORY_SCOPE_AGENT);
      }
      while (__hip_atomic_load(&bar[0], __ATOMIC_RELAXED, __HIP_MEMORY_SCOPE_AGENT) < gen)
        __builtin_amdgcn_s_sleep(1);
    }
    __syncthreads();
    __builtin_amdgcn_fence(__ATOMIC_ACQUIRE, "agent");
  };

  // ---- prologue: gates0[0] = z@Whh0 + b (pred=0); accG1 = z@Whh1 carry ----
  do_pass(h0buf, w_hh0, w_hh1, accG0, accG1);
  grid_barrier();                         // all reads of z done before overwrite
  reduce_finals(accG0, sb0p);
  elementwise(c0, h0buf, false);          // h0[0] -> h0buf
  grid_barrier();                         // publish h0[0]

  for (int t=0; t<TSTEPS; ++t) {
    // gates1[t] completes (h0[t]@Wih1 + carry); gates0[t+1] partial (h0[t]@Whh0)
    do_pass(h0buf, w_ih1, w_hh0, accG1, accG0);
    reduce_finals(accG1, sb1);
    elementwise(c1, h1buf, true);         // h1[t] + pred partials
    grid_barrier();                       // publish h1[t], predpart

    // gates0[t+1] completes (h1[t]@Wfold, folded pred); gates1[t+1] partial (h1[t]@Whh1)
    do_pass(h1buf, w_fold, w_hh1, accG0, accG1);
    reduce_finals(accG0, sb0f);
    elementwise(c0, h0buf, false);        // h0[t+1]

    // pred[t] reduction: block b (<128) sums 256 WG partials -> recovered[b][t]
    if (wg < BATCH) {
      float v = (tid < 256) ? predpart[(wg<<8) + tid] : 0.f;
      #pragma unroll
      for (int s=1; s<64; s<<=1) v += __shfl_xor(v, s);
      if (lane == 0) pr[wid] = v;
      __syncthreads();
      if (tid == 0) {
        float s = pr[0]+pr[1]+pr[2]+pr[3]+pr[4]+pr[5]+pr[6]+pr[7] + bout_s;
        out[1 + wg*TSTEPS + t] = s;
        float d = seq[wg*TSTEPS + t] - s;
        lossacc += d*d;                   // per-batch running loss, in-register
      }
      __syncthreads();
    }
    grid_barrier();                       // publish h0[t+1]
  }

  // ---- loss epilogue ----
  if (wg < BATCH && tid == 0)
    __hip_atomic_store(&losspart[wg], lossacc, __ATOMIC_RELAXED, __HIP_MEMORY_SCOPE_AGENT);
  grid_barrier();
  if (wg == 0 && tid == 0) {
    double s = 0.0;
    for (int j=0;j<BATCH;j++) s += (double)losspart[j];
    out[0] = (float)(s / 65536.0);
  }
}

extern "C" void kernel_launch(void* const* d_in, const int* in_sizes, int n_in,
                              void* d_out, int out_size, void* d_ws, size_t ws_size,
                              hipStream_t stream)
{
  const float* seq  = (const float*)d_in[0];
  const float* z    = (const float*)d_in[1];
  const float* Wih0 = (const float*)d_in[2];
  const float* Whh0 = (const float*)d_in[3];
  const float* bih0 = (const float*)d_in[4];
  const float* bhh0 = (const float*)d_in[5];
  const float* Wih1 = (const float*)d_in[6];
  const float* Whh1 = (const float*)d_in[7];
  const float* bih1 = (const float*)d_in[8];
  const float* bhh1 = (const float*)d_in[9];
  const float* Wout = (const float*)d_in[10];
  const float* bout = (const float*)d_in[11];
  float* out = (float*)d_out;

  char* ws = (char*)d_ws;
  unsigned short* h0buf = (unsigned short*)(ws);                    // 256KB
  unsigned short* h1buf = (unsigned short*)(ws + 256*1024);         // 256KB
  float* predpart = (float*)(ws + 512*1024);                        // 128KB [b][wg]
  float* losspart = (float*)(ws + 640*1024);                        // 1KB
  unsigned* bar   = (unsigned*)(ws + 644*1024);                     // 2KB barrier state

  hipLaunchKernelGGL(init_kernel, dim3(128), dim3(256), 0, stream, z, h0buf, bar);

  void* args[] = { (void*)&seq, (void*)&z, (void*)&Wih0, (void*)&Whh0, (void*)&bih0, (void*)&bhh0,
                   (void*)&Wih1, (void*)&Whh1, (void*)&bih1, (void*)&bhh1, (void*)&Wout, (void*)&bout,
                   (void*)&out, (void*)&h0buf, (void*)&h1buf, (void*)&predpart, (void*)&losspart, (void*)&bar };
  hipLaunchCooperativeKernel((void*)lstm_kernel, dim3(NWG), dim3(NTHR), args, 0u, stream);
}

// Round 5
// 28228.693 us; speedup vs baseline: 2.4592x; 1.0057x over previous
//
#include <hip/hip_runtime.h>
#include <hip/hip_bf16.h>

#define HID 1024
#define BATCH 128
#define TSTEPS 512
#define NWG 256
#define NTHR 512

typedef __bf16 bf16x4 __attribute__((ext_vector_type(4)));
typedef __bf16 bf16x8 __attribute__((ext_vector_type(8)));
typedef float f32x4 __attribute__((ext_vector_type(4)));

#define ASTORE_U(p,v) __hip_atomic_store((p),(v),__ATOMIC_RELAXED,__HIP_MEMORY_SCOPE_AGENT)
#define ASTORE_F(p,v) __hip_atomic_store((p),(v),__ATOMIC_RELAXED,__HIP_MEMORY_SCOPE_AGENT)
#define ALOAD_U(p)    __hip_atomic_load((p),__ATOMIC_RELAXED,__HIP_MEMORY_SCOPE_AGENT)
#define ALOAD_F(p)    __hip_atomic_load((p),__ATOMIC_RELAXED,__HIP_MEMORY_SCOPE_AGENT)
#define AADD_U(p,v)   __hip_atomic_fetch_add((p),(v),__ATOMIC_RELAXED,__HIP_MEMORY_SCOPE_AGENT)

__device__ __forceinline__ float sigm(float x){ return 1.f/(1.f+__expf(-x)); }

__device__ __forceinline__ bf16x8 cvt8(const float* __restrict__ p){
  bf16x8 r;
  #pragma unroll
  for (int i=0;i<8;i++) r[i] = (__bf16)p[i];
  return r;
}
__device__ __forceinline__ bf16x8 cvt8s(const float* __restrict__ p, float s){
  bf16x8 r;
  #pragma unroll
  for (int i=0;i<8;i++) r[i] = (__bf16)(p[i]*s);
  return r;
}

// staging layout: element (u,b) at  (u>>2)*512 + b*4 + (u&3)   [bf16]
// -> per-WG block of 512 elements is contiguous (coalesced stores);
//    A-frag reads are 2x 8B per fragment.
__global__ void init_kernel(const float* __restrict__ z,
                            unsigned short* __restrict__ st0,
                            unsigned* __restrict__ bar){
  int i = blockIdx.x*blockDim.x + threadIdx.x;     // 65536 threads
  if (i < 1024) bar[i] = 0u;
  for (int idx = i; idx < BATCH*HID; idx += 65536){
    int blk = idx >> 9, rem = idx & 511, b = rem >> 2, du = rem & 3;
    st0[idx] = __builtin_bit_cast(unsigned short, (__bf16)z[b*HID + blk*4 + du]);
  }
}

// barrier word offsets (unsigned), each slot in its own 128B line, all < 1024 words (4KB)
#define GRP_CTR(g)  ((g)*32)
#define MID_CTR     256
#define GRP_FLAG(g) (320 + (g)*32)

__global__ __launch_bounds__(NTHR, 2) void lstm_kernel(
    const float* __restrict__ seq,
    const float* __restrict__ z,
    const float* __restrict__ Wih0, const float* __restrict__ Whh0,
    const float* __restrict__ bih0, const float* __restrict__ bhh0,
    const float* __restrict__ Wih1, const float* __restrict__ Whh1,
    const float* __restrict__ bih1, const float* __restrict__ bhh1,
    const float* __restrict__ Wout, const float* __restrict__ bout,
    float* __restrict__ out,
    unsigned short* __restrict__ st0,
    unsigned short* __restrict__ st1,
    float* __restrict__ predpart,   // [wg][b]
    float* __restrict__ shalf,      // [b] upper-half partial sums
    float* __restrict__ losspart,
    unsigned* __restrict__ bar)
{
  const int tid  = threadIdx.x;
  const int wg   = blockIdx.x;
  const int wid  = tid >> 6;
  const int lane = tid & 63;
  const int u0   = wg << 2;          // owns units [u0,u0+4) in both layers

  __shared__ float red[8][2048];     // 8 wave K-partials, XOR-skewed (bijective)
  __shared__ float finals2[16*132];  // [col][b], padded stride 132
  __shared__ float pr2[2];
  __shared__ float sb0p[16], sb0f[16], sb1[16];

  const float bout_s = bout[0];

  if (tid < 16) {
    int g = tid >> 2, du = tid & 3;
    int gc = g*HID + u0 + du;
    float bp = bih0[gc] + bhh0[gc];
    sb0p[tid] = bp;                       // layer0 bias, t==0 (pred = 0)
    sb0f[tid] = bp + Wih0[gc]*bout_s;     // layer0 bias + folded b_out term
    sb1[tid]  = bih1[gc] + bhh1[gc];
  }

  const int eb  = tid >> 2;
  const int edu = tid & 3;
  const float wout_u = Wout[u0 + edu];
  float c0 = z[eb*HID + u0 + edu];
  float c1 = c0;
  float lossacc = 0.f;
  float myhalf  = 0.f;                    // thread0 of wg<128: lower-half pred sum

  // ---- persistent weight fragments (MFMA B-operand layout) ----
  const int bcol = lane & 15;
  const int gcol = (bcol >> 2)*HID + u0 + (bcol & 3);
  const int ksub = (lane >> 4) << 3;
  bf16x8 w_hh0[4], w_ih1[4], w_hh1[4], w_fold[4];
  {
    const float wih0c = Wih0[gcol];
    #pragma unroll
    for (int kt=0; kt<4; ++kt) {
      int k0 = (wid << 7) + (kt << 5) + ksub;
      w_hh0[kt]  = cvt8(Whh0 + gcol*HID + k0);
      w_ih1[kt]  = cvt8(Wih1 + gcol*HID + k0);
      w_hh1[kt]  = cvt8(Whh1 + gcol*HID + k0);
      w_fold[kt] = cvt8s(Wout + k0, wih0c);
    }
  }

  f32x4 accG0[8], accG1[8];
  #pragma unroll
  for (int m=0;m<8;m++){ accG0[m] = f32x4{0,0,0,0}; accG1[m] = f32x4{0,0,0,0}; }

  unsigned gen = 0;

  const int rowoff = (lane & 15) * 4;
  const int blk0   = wid*32 + (lane>>4)*2;

  auto do_pass = [&](const unsigned short* __restrict__ src,
                     const bf16x8* wA, const bf16x8* wB,
                     f32x4* accA, f32x4* accB){
    #pragma unroll
    for (int kt=0; kt<4; ++kt){
      bf16x8 af[8];
      #pragma unroll
      for (int m=0;m<8;m++){
        const unsigned short* p = src + (size_t)((blk0 + kt*8)*512 + m*64 + rowoff);
        bf16x4 lo = *reinterpret_cast<const bf16x4*>(p);
        bf16x4 hi = *reinterpret_cast<const bf16x4*>(p + 512);
        af[m] = __builtin_shufflevector(lo, hi, 0,1,2,3,4,5,6,7);
      }
      #pragma unroll
      for (int m=0;m<8;m++){
        accA[m] = __builtin_amdgcn_mfma_f32_16x16x32_bf16(af[m], wA[kt], accA[m], 0, 0, 0);
        accB[m] = __builtin_amdgcn_mfma_f32_16x16x32_bf16(af[m], wB[kt], accB[m], 0, 0, 0);
      }
    }
  };

  // 8 wave K-partials -> finals2[col][b] (+bias); zeroes acc.
  // XOR skew on bits 3-4 by lane-group: bijective (involution), write side
  // s = lane>>4 equals read side (i>>6)&3 since i bits 6-7 == lane>>4.
  auto reduce_finals = [&](f32x4* acc, const float* sbias){
    const int lrow = lane >> 4;
    const int wbase0 = (lrow << 6) + (lane & 15);
    const int skw = lrow << 3;
    #pragma unroll
    for (int m=0;m<8;m++){
      #pragma unroll
      for (int e=0;e<4;e++)
        red[wid][(wbase0 + (e<<4) + (m<<8)) ^ skw] = acc[m][e];
    }
    __syncthreads();
    #pragma unroll
    for (int j=0;j<4;j++){
      int i = tid + j*512;
      int a = i ^ ((((i>>6)&3))<<3);
      float s = red[0][a]+red[1][a]+red[2][a]+red[3][a]
              + red[4][a]+red[5][a]+red[6][a]+red[7][a] + sbias[i&15];
      finals2[(i&15)*132 + (i>>4)] = s;
    }
    __syncthreads();
    #pragma unroll
    for (int m=0;m<8;m++) acc[m] = f32x4{0,0,0,0};
  };

  auto elementwise = [&](float& c, unsigned short* __restrict__ stdst, bool dopred){
    float gi = finals2[(edu   )*132 + eb];
    float gf = finals2[(edu+ 4)*132 + eb];
    float gg = finals2[(edu+ 8)*132 + eb];
    float go = finals2[(edu+12)*132 + eb];
    float fi = sigm(gi), ff = sigm(gf), fo = sigm(go);
    c = ff*c + fi*tanhf(gg);
    float h = fo*tanhf(c);
    unsigned h16 = (unsigned)__builtin_bit_cast(unsigned short, (__bf16)h);
    unsigned other = (unsigned)__shfl_xor((int)h16, 1);
    if (!(tid & 1)) {
      unsigned word = h16 | (other << 16);            // coalesced: dword at elem tid
      ASTORE_U((unsigned*)(stdst + wg*512 + tid), word);
    }
    if (dopred){
      float pv = h * wout_u;
      pv += __shfl_xor(pv, 1);
      pv += __shfl_xor(pv, 2);
      if (edu == 0) ASTORE_F(&predpart[wg*128 + eb], pv);
    }
  };

  // padded counters, fan-out release; acquire fence after exit (round-2-proven)
  auto grid_barrier = [&](){
    __syncthreads();                       // drains vmcnt -> sc1 stores at L3
    ++gen;
    if (tid == 0) {
      unsigned old = AADD_U(&bar[GRP_CTR(wg & 7)], 1u);
      if (old == gen*32u - 1u) {
        unsigned r = AADD_U(&bar[MID_CTR], 1u);
        if (r == gen*8u - 1u) {
          #pragma unroll
          for (int g2=0; g2<8; ++g2) ASTORE_U(&bar[GRP_FLAG(g2)], gen);
        }
      }
      while (ALOAD_U(&bar[GRP_FLAG(wg & 7)]) < gen)
        __builtin_amdgcn_s_sleep(4);
    }
    __syncthreads();
    __builtin_amdgcn_fence(__ATOMIC_ACQUIRE, "agent");
  };

  // ---- prologue: accG0 = z@Whh0 (gates0[0]); accG1 = z@Whh1 (carry) ----
  do_pass(st0, w_hh0, w_hh1, accG0, accG1);
  grid_barrier();                          // all WGs consumed z-staging
  reduce_finals(accG0, sb0p);
  elementwise(c0, st0, false);             // h0[0] -> st0
  grid_barrier();                          // publish h0[0]

  for (int t=0; t<TSTEPS; ++t) {
    // ---- Phase A: gates1[t] completes; gates0[t+1] h0-part ----
    do_pass(st0, w_ih1, w_hh0, accG1, accG0);
    float oh = 0.f;
    if (t > 0 && wg < BATCH && tid == 0) oh = ALOAD_F(&shalf[wg]);   // early load
    reduce_finals(accG1, sb1);
    if (t > 0 && wg < BATCH && tid == 0) {
      float pred = myhalf + oh + bout_s;                   // finalize pred[t-1]
      out[1 + wg*TSTEPS + (t-1)] = pred;
      float d = seq[wg*TSTEPS + (t-1)] - pred;
      lossacc += d*d;
    }
    elementwise(c1, st1, true);            // h1[t] + pred partials
    grid_barrier();                        // publish h1[t], predpart

    // ---- Phase B: gates0[t+1] completes via fold; gates1[t+1] h1-part ----
    float hred = 0.f;
    if (tid < 128)
      hred = ALOAD_F(&predpart[((wg >> 7)*128 + tid)*128 + (wg & 127)]);  // early
    do_pass(st1, w_fold, w_hh1, accG0, accG1);
    hred += __shfl_xor(hred, 1);  hred += __shfl_xor(hred, 2);
    hred += __shfl_xor(hred, 4);  hred += __shfl_xor(hred, 8);
    hred += __shfl_xor(hred, 16); hred += __shfl_xor(hred, 32);
    if (tid == 0)  pr2[0] = hred;
    if (tid == 64) pr2[1] = hred;
    reduce_finals(accG0, sb0f);            // syncs make pr2 visible to tid0
    if (tid == 0) {
      float hs = pr2[0] + pr2[1];
      if (wg >= BATCH) ASTORE_F(&shalf[wg - BATCH], hs);
      else             myhalf = hs;
    }
    elementwise(c0, st0, false);           // h0[t+1]
    grid_barrier();                        // publish h0[t+1], shalf
  }

  // ---- epilogue: last pred + loss ----
  if (wg < BATCH && tid == 0) {
    float oh2 = ALOAD_F(&shalf[wg]);
    float pred = myhalf + oh2 + bout_s;
    out[1 + wg*TSTEPS + (TSTEPS-1)] = pred;
    float d = seq[wg*TSTEPS + (TSTEPS-1)] - pred;
    lossacc += d*d;
    ASTORE_F(&losspart[wg], lossacc);
  }
  grid_barrier();
  if (wg == 0) {
    float v = 0.f;
    if (tid < BATCH) v = ALOAD_F(&losspart[tid]);
    v += __shfl_xor(v, 1);  v += __shfl_xor(v, 2);
    v += __shfl_xor(v, 4);  v += __shfl_xor(v, 8);
    v += __shfl_xor(v, 16); v += __shfl_xor(v, 32);
    if (tid == 0)  pr2[0] = v;
    if (tid == 64) pr2[1] = v;
    __syncthreads();
    if (tid == 0) out[0] = (pr2[0] + pr2[1]) * (1.f/65536.f);
  }
}

extern "C" void kernel_launch(void* const* d_in, const int* in_sizes, int n_in,
                              void* d_out, int out_size, void* d_ws, size_t ws_size,
                              hipStream_t stream)
{
  const float* seq  = (const float*)d_in[0];
  const float* z    = (const float*)d_in[1];
  const float* Wih0 = (const float*)d_in[2];
  const float* Whh0 = (const float*)d_in[3];
  const float* bih0 = (const float*)d_in[4];
  const float* bhh0 = (const float*)d_in[5];
  const float* Wih1 = (const float*)d_in[6];
  const float* Whh1 = (const float*)d_in[7];
  const float* bih1 = (const float*)d_in[8];
  const float* bhh1 = (const float*)d_in[9];
  const float* Wout = (const float*)d_in[10];
  const float* bout = (const float*)d_in[11];
  float* out = (float*)d_out;

  // Compacted layout: max offset 645KB (<= round-2-proven footprint).
  char* ws = (char*)d_ws;
  unsigned short* st0 = (unsigned short*)(ws);                    // 256KB @ 0
  unsigned short* st1 = (unsigned short*)(ws + 256*1024);         // 256KB @ 256K
  unsigned* bar   = (unsigned*)(ws + 512*1024);                   // 4KB  @ 512K
  float* predpart = (float*)(ws + 516*1024);                      // 128KB @ 516K
  float* shalf    = (float*)(ws + 644*1024);                      // 512B @ 644K
  float* losspart = (float*)(ws + 644*1024 + 512);                // 512B

  hipLaunchKernelGGL(init_kernel, dim3(256), dim3(256), 0, stream, z, st0, bar);

  void* args[] = { (void*)&seq, (void*)&z, (void*)&Wih0, (void*)&Whh0, (void*)&bih0, (void*)&bhh0,
                   (void*)&Wih1, (void*)&Whh1, (void*)&bih1, (void*)&bhh1, (void*)&Wout, (void*)&bout,
                   (void*)&out, (void*)&st0, (void*)&st1, (void*)&predpart, (void*)&shalf,
                   (void*)&losspart, (void*)&bar };
  hipLaunchCooperativeKernel((void*)lstm_kernel, dim3(NWG), dim3(NTHR), args, 0u, stream);
}

// Round 6
// 11059.826 us; speedup vs baseline: 6.2767x; 2.5524x over previous
//
#include <hip/hip_runtime.h>
#include <hip/hip_bf16.h>

#define HID 1024
#define BATCH 128
#define TSTEPS 512
#define NWG 256
#define NTHR 512

typedef __bf16 bf16x4 __attribute__((ext_vector_type(4)));
typedef __bf16 bf16x8 __attribute__((ext_vector_type(8)));
typedef float f32x4 __attribute__((ext_vector_type(4)));

#define ASTORE_U(p,v) __hip_atomic_store((p),(v),__ATOMIC_RELAXED,__HIP_MEMORY_SCOPE_AGENT)
#define ASTORE_F(p,v) __hip_atomic_store((p),(v),__ATOMIC_RELAXED,__HIP_MEMORY_SCOPE_AGENT)
#define ALOAD_U(p)    __hip_atomic_load((p),__ATOMIC_RELAXED,__HIP_MEMORY_SCOPE_AGENT)
#define ALOAD_F(p)    __hip_atomic_load((p),__ATOMIC_RELAXED,__HIP_MEMORY_SCOPE_AGENT)
#define ALOAD_ULL(p)  __hip_atomic_load((p),__ATOMIC_RELAXED,__HIP_MEMORY_SCOPE_AGENT)
#define AADD_U(p,v)   __hip_atomic_fetch_add((p),(v),__ATOMIC_RELAXED,__HIP_MEMORY_SCOPE_AGENT)

__device__ __forceinline__ float sigm(float x){ return 1.f/(1.f+__expf(-x)); }

__device__ __forceinline__ bf16x8 cvt8(const float* __restrict__ p){
  bf16x8 r;
  #pragma unroll
  for (int i=0;i<8;i++) r[i] = (__bf16)p[i];
  return r;
}
__device__ __forceinline__ bf16x8 cvt8s(const float* __restrict__ p, float s){
  bf16x8 r;
  #pragma unroll
  for (int i=0;i<8;i++) r[i] = (__bf16)(p[i]*s);
  return r;
}

// staging layout: element (u,b) at  (u>>2)*512 + b*4 + (u&3)   [bf16]
// -> per-WG block of 512 elements is contiguous (coalesced stores);
//    A-frag reads are 2x 8B per fragment.
__global__ void init_kernel(const float* __restrict__ z,
                            unsigned short* __restrict__ st0,
                            unsigned* __restrict__ bar){
  int i = blockIdx.x*blockDim.x + threadIdx.x;     // 65536 threads
  if (i < 1024) bar[i] = 0u;
  for (int idx = i; idx < BATCH*HID; idx += 65536){
    int blk = idx >> 9, rem = idx & 511, b = rem >> 2, du = rem & 3;
    st0[idx] = __builtin_bit_cast(unsigned short, (__bf16)z[b*HID + blk*4 + du]);
  }
}

// barrier word offsets (unsigned), each slot in its own 128B line, all < 1024 words (4KB)
#define GRP_CTR(g)  ((g)*32)
#define MID_CTR     256
#define GRP_FLAG(g) (320 + (g)*32)

__global__ __launch_bounds__(NTHR, 2) void lstm_kernel(
    const float* __restrict__ seq,
    const float* __restrict__ z,
    const float* __restrict__ Wih0, const float* __restrict__ Whh0,
    const float* __restrict__ bih0, const float* __restrict__ bhh0,
    const float* __restrict__ Wih1, const float* __restrict__ Whh1,
    const float* __restrict__ bih1, const float* __restrict__ bhh1,
    const float* __restrict__ Wout, const float* __restrict__ bout,
    float* __restrict__ out,
    unsigned short* __restrict__ st0,
    unsigned short* __restrict__ st1,
    float* __restrict__ predpart,   // [wg][b]
    float* __restrict__ shalf,      // [b] upper-half partial sums
    float* __restrict__ losspart,
    unsigned* __restrict__ bar)
{
  const int tid  = threadIdx.x;
  const int wg   = blockIdx.x;
  const int wid  = tid >> 6;
  const int lane = tid & 63;
  const int u0   = wg << 2;          // owns units [u0,u0+4) in both layers

  __shared__ float red[8][2048];     // 8 wave K-partials, XOR-skewed (bijective)
  __shared__ float finals2[16*132];  // [col][b], padded stride 132
  __shared__ float pr2[2];
  __shared__ float sb0p[16], sb0f[16], sb1[16];

  const float bout_s = bout[0];

  if (tid < 16) {
    int g = tid >> 2, du = tid & 3;
    int gc = g*HID + u0 + du;
    float bp = bih0[gc] + bhh0[gc];
    sb0p[tid] = bp;                       // layer0 bias, t==0 (pred = 0)
    sb0f[tid] = bp + Wih0[gc]*bout_s;     // layer0 bias + folded b_out term
    sb1[tid]  = bih1[gc] + bhh1[gc];
  }

  const int eb  = tid >> 2;
  const int edu = tid & 3;
  const float wout_u = Wout[u0 + edu];
  float c0 = z[eb*HID + u0 + edu];
  float c1 = c0;
  float lossacc = 0.f;
  float myhalf  = 0.f;                    // thread0 of wg<128: lower-half pred sum

  // ---- persistent weight fragments (MFMA B-operand layout) ----
  const int bcol = lane & 15;
  const int gcol = (bcol >> 2)*HID + u0 + (bcol & 3);
  const int ksub = (lane >> 4) << 3;
  bf16x8 w_hh0[4], w_ih1[4], w_hh1[4], w_fold[4];
  {
    const float wih0c = Wih0[gcol];
    #pragma unroll
    for (int kt=0; kt<4; ++kt) {
      int k0 = (wid << 7) + (kt << 5) + ksub;
      w_hh0[kt]  = cvt8(Whh0 + gcol*HID + k0);
      w_ih1[kt]  = cvt8(Wih1 + gcol*HID + k0);
      w_hh1[kt]  = cvt8(Whh1 + gcol*HID + k0);
      w_fold[kt] = cvt8s(Wout + k0, wih0c);
    }
  }

  f32x4 accG0[8], accG1[8];
  #pragma unroll
  for (int m=0;m<8;m++){ accG0[m] = f32x4{0,0,0,0}; accG1[m] = f32x4{0,0,0,0}; }

  unsigned gen = 0;

  const int rowoff = (lane & 15) * 4;
  const int blk0   = wid*32 + (lane>>4)*2;

  // Staging reads are relaxed AGENT atomic 8B loads (sc0 sc1): always served
  // at the coherence point (L3), never stale L1/L2 -> NO acquire fence needed
  // anywhere. This removes 2048 buffer_inv ops per phase (the round-2/5
  // fixed 27.5us/phase cost theory).
  auto do_pass = [&](const unsigned short* __restrict__ src,
                     const bf16x8* wA, const bf16x8* wB,
                     f32x4* accA, f32x4* accB){
    #pragma unroll
    for (int kt=0; kt<4; ++kt){
      bf16x8 af[8];
      #pragma unroll
      for (int m=0;m<8;m++){
        const unsigned short* p = src + (size_t)((blk0 + kt*8)*512 + m*64 + rowoff);
        unsigned long long lo64 = ALOAD_ULL((const unsigned long long*)p);
        unsigned long long hi64 = ALOAD_ULL((const unsigned long long*)(p + 512));
        bf16x4 lo = __builtin_bit_cast(bf16x4, lo64);
        bf16x4 hi = __builtin_bit_cast(bf16x4, hi64);
        af[m] = __builtin_shufflevector(lo, hi, 0,1,2,3,4,5,6,7);
      }
      #pragma unroll
      for (int m=0;m<8;m++){
        accA[m] = __builtin_amdgcn_mfma_f32_16x16x32_bf16(af[m], wA[kt], accA[m], 0, 0, 0);
        accB[m] = __builtin_amdgcn_mfma_f32_16x16x32_bf16(af[m], wB[kt], accB[m], 0, 0, 0);
      }
    }
  };

  // 8 wave K-partials -> finals2[col][b] (+bias); zeroes acc.
  // XOR skew on bits 3-4 by lane-group: bijective (involution), write side
  // s = lane>>4 equals read side (i>>6)&3 since i bits 6-7 == lane>>4.
  auto reduce_finals = [&](f32x4* acc, const float* sbias){
    const int lrow = lane >> 4;
    const int wbase0 = (lrow << 6) + (lane & 15);
    const int skw = lrow << 3;
    #pragma unroll
    for (int m=0;m<8;m++){
      #pragma unroll
      for (int e=0;e<4;e++)
        red[wid][(wbase0 + (e<<4) + (m<<8)) ^ skw] = acc[m][e];
    }
    __syncthreads();
    #pragma unroll
    for (int j=0;j<4;j++){
      int i = tid + j*512;
      int a = i ^ ((((i>>6)&3))<<3);
      float s = red[0][a]+red[1][a]+red[2][a]+red[3][a]
              + red[4][a]+red[5][a]+red[6][a]+red[7][a] + sbias[i&15];
      finals2[(i&15)*132 + (i>>4)] = s;
    }
    __syncthreads();
    #pragma unroll
    for (int m=0;m<8;m++) acc[m] = f32x4{0,0,0,0};
  };

  auto elementwise = [&](float& c, unsigned short* __restrict__ stdst, bool dopred){
    float gi = finals2[(edu   )*132 + eb];
    float gf = finals2[(edu+ 4)*132 + eb];
    float gg = finals2[(edu+ 8)*132 + eb];
    float go = finals2[(edu+12)*132 + eb];
    float fi = sigm(gi), ff = sigm(gf), fo = sigm(go);
    c = ff*c + fi*tanhf(gg);
    float h = fo*tanhf(c);
    unsigned h16 = (unsigned)__builtin_bit_cast(unsigned short, (__bf16)h);
    unsigned other = (unsigned)__shfl_xor((int)h16, 1);
    if (!(tid & 1)) {
      unsigned word = h16 | (other << 16);            // coalesced: dword at elem tid
      ASTORE_U((unsigned*)(stdst + wg*512 + tid), word);
    }
    if (dopred){
      float pv = h * wout_u;
      pv += __shfl_xor(pv, 1);
      pv += __shfl_xor(pv, 2);
      if (edu == 0) ASTORE_F(&predpart[wg*128 + eb], pv);
    }
  };

  // padded counters, fan-out release. NO acquire fence: cross-WG data is read
  // exclusively via sc1 atomic loads (staging, predpart, shalf, losspart).
  auto grid_barrier = [&](){
    __syncthreads();                       // drains vmcnt -> sc1 stores at L3
    ++gen;
    if (tid == 0) {
      unsigned old = AADD_U(&bar[GRP_CTR(wg & 7)], 1u);
      if (old == gen*32u - 1u) {
        unsigned r = AADD_U(&bar[MID_CTR], 1u);
        if (r == gen*8u - 1u) {
          #pragma unroll
          for (int g2=0; g2<8; ++g2) ASTORE_U(&bar[GRP_FLAG(g2)], gen);
        }
      }
      while (ALOAD_U(&bar[GRP_FLAG(wg & 7)]) < gen)
        __builtin_amdgcn_s_sleep(4);
    }
    __syncthreads();
  };

  // ---- prologue: accG0 = z@Whh0 (gates0[0]); accG1 = z@Whh1 (carry) ----
  do_pass(st0, w_hh0, w_hh1, accG0, accG1);
  grid_barrier();                          // all WGs consumed z-staging
  reduce_finals(accG0, sb0p);
  elementwise(c0, st0, false);             // h0[0] -> st0
  grid_barrier();                          // publish h0[0]

  for (int t=0; t<TSTEPS; ++t) {
    // ---- Phase A: gates1[t] completes; gates0[t+1] h0-part ----
    do_pass(st0, w_ih1, w_hh0, accG1, accG0);
    float oh = 0.f;
    if (t > 0 && wg < BATCH && tid == 0) oh = ALOAD_F(&shalf[wg]);   // early load
    reduce_finals(accG1, sb1);
    if (t > 0 && wg < BATCH && tid == 0) {
      float pred = myhalf + oh + bout_s;                   // finalize pred[t-1]
      out[1 + wg*TSTEPS + (t-1)] = pred;
      float d = seq[wg*TSTEPS + (t-1)] - pred;
      lossacc += d*d;
    }
    elementwise(c1, st1, true);            // h1[t] + pred partials
    grid_barrier();                        // publish h1[t], predpart

    // ---- Phase B: gates0[t+1] completes via fold; gates1[t+1] h1-part ----
    float hred = 0.f;
    if (tid < 128)
      hred = ALOAD_F(&predpart[((wg >> 7)*128 + tid)*128 + (wg & 127)]);  // early
    do_pass(st1, w_fold, w_hh1, accG0, accG1);
    hred += __shfl_xor(hred, 1);  hred += __shfl_xor(hred, 2);
    hred += __shfl_xor(hred, 4);  hred += __shfl_xor(hred, 8);
    hred += __shfl_xor(hred, 16); hred += __shfl_xor(hred, 32);
    if (tid == 0)  pr2[0] = hred;
    if (tid == 64) pr2[1] = hred;
    reduce_finals(accG0, sb0f);            // syncs make pr2 visible to tid0
    if (tid == 0) {
      float hs = pr2[0] + pr2[1];
      if (wg >= BATCH) ASTORE_F(&shalf[wg - BATCH], hs);
      else             myhalf = hs;
    }
    elementwise(c0, st0, false);           // h0[t+1]
    grid_barrier();                        // publish h0[t+1], shalf
  }

  // ---- epilogue: last pred + loss ----
  if (wg < BATCH && tid == 0) {
    float oh2 = ALOAD_F(&shalf[wg]);
    float pred = myhalf + oh2 + bout_s;
    out[1 + wg*TSTEPS + (TSTEPS-1)] = pred;
    float d = seq[wg*TSTEPS + (TSTEPS-1)] - pred;
    lossacc += d*d;
    ASTORE_F(&losspart[wg], lossacc);
  }
  grid_barrier();
  if (wg == 0) {
    float v = 0.f;
    if (tid < BATCH) v = ALOAD_F(&losspart[tid]);
    v += __shfl_xor(v, 1);  v += __shfl_xor(v, 2);
    v += __shfl_xor(v, 4);  v += __shfl_xor(v, 8);
    v += __shfl_xor(v, 16); v += __shfl_xor(v, 32);
    if (tid == 0)  pr2[0] = v;
    if (tid == 64) pr2[1] = v;
    __syncthreads();
    if (tid == 0) out[0] = (pr2[0] + pr2[1]) * (1.f/65536.f);
  }
}

extern "C" void kernel_launch(void* const* d_in, const int* in_sizes, int n_in,
                              void* d_out, int out_size, void* d_ws, size_t ws_size,
                              hipStream_t stream)
{
  const float* seq  = (const float*)d_in[0];
  const float* z    = (const float*)d_in[1];
  const float* Wih0 = (const float*)d_in[2];
  const float* Whh0 = (const float*)d_in[3];
  const float* bih0 = (const float*)d_in[4];
  const float* bhh0 = (const float*)d_in[5];
  const float* Wih1 = (const float*)d_in[6];
  const float* Whh1 = (const float*)d_in[7];
  const float* bih1 = (const float*)d_in[8];
  const float* bhh1 = (const float*)d_in[9];
  const float* Wout = (const float*)d_in[10];
  const float* bout = (const float*)d_in[11];
  float* out = (float*)d_out;

  // Compacted layout: max offset 645KB (<= round-2-proven footprint).
  char* ws = (char*)d_ws;
  unsigned short* st0 = (unsigned short*)(ws);                    // 256KB @ 0
  unsigned short* st1 = (unsigned short*)(ws + 256*1024);         // 256KB @ 256K
  unsigned* bar   = (unsigned*)(ws + 512*1024);                   // 4KB  @ 512K
  float* predpart = (float*)(ws + 516*1024);                      // 128KB @ 516K
  float* shalf    = (float*)(ws + 644*1024);                      // 512B @ 644K
  float* losspart = (float*)(ws + 644*1024 + 512);                // 512B

  hipLaunchKernelGGL(init_kernel, dim3(256), dim3(256), 0, stream, z, st0, bar);

  void* args[] = { (void*)&seq, (void*)&z, (void*)&Wih0, (void*)&Whh0, (void*)&bih0, (void*)&bhh0,
                   (void*)&Wih1, (void*)&Whh1, (void*)&bih1, (void*)&bhh1, (void*)&Wout, (void*)&bout,
                   (void*)&out, (void*)&st0, (void*)&st1, (void*)&predpart, (void*)&shalf,
                   (void*)&losspart, (void*)&bar };
  hipLaunchCooperativeKernel((void*)lstm_kernel, dim3(NWG), dim3(NTHR), args, 0u, stream);
}